// Round 3
// baseline (1885.432 us; speedup 1.0000x reference)
//
#include <hip/hip_runtime.h>

#define NUM_PL 50000
#define NUM_TR 100000
#define NUM_AR 10000
#define NN     160000          // NUM_PL + NUM_TR + NUM_AR
#define HID    64
#define FEAT   128
#define E_PLTR 2000000
#define E_TRAR 100000
#define E_TOT  4200000         // 2*E_PLTR + 2*E_TRAR
#define OFF_TR 50000
#define OFF_AR 150000

#define BIN_CHUNK 8192
#define NBLK_BIN  513          // ceil(E_TOT / BIN_CHUNK)
#define NBUCK     625          // NN / 256 (exact)
#define TABW      626          // NBUCK + 1
#define PKD_CAP   (NBLK_BIN * BIN_CHUNK)

#define WSTRIDE 68             // 64 + 4: keeps float4 rows 16B-aligned,
                               // bank = (4j+4k4)%32 -> no excess conflicts

// edge id -> (src,dst) global node ids, matching the reference concatenation
__device__ __forceinline__ void edge_sd(
    int e, const int* __restrict__ pls, const int* __restrict__ pld,
    const int* __restrict__ tas, const int* __restrict__ tad, int& s, int& d) {
  if (e < E_PLTR)                   { s = pls[e];               d = pld[e] + OFF_TR; }
  else if (e < 2 * E_PLTR)          { int i = e - E_PLTR;
                                      s = pld[i] + OFF_TR;      d = pls[i]; }
  else if (e < 2 * E_PLTR + E_TRAR) { int i = e - 2 * E_PLTR;
                                      s = tas[i] + OFF_TR;      d = tad[i] + OFF_AR; }
  else                              { int i = e - 2 * E_PLTR - E_TRAR;
                                      s = tad[i] + OFF_AR;      d = tas[i] + OFF_TR; }
}

__device__ __forceinline__ float rlane(float v, int l) {
  return __uint_as_float((unsigned)__builtin_amdgcn_readlane(__float_as_uint(v), l));
}

// ---------------------------------------------------------------------------
// x[pl] = playlist_emb + type_emb[0];  x[ar] = artist_emb + type_emb[2]
// ---------------------------------------------------------------------------
__global__ __launch_bounds__(256) void k_init_emb(
    const float* __restrict__ pl_emb, const float* __restrict__ ar_emb,
    const float* __restrict__ type_emb, float* __restrict__ x) {
  int tid = blockIdx.x * 256 + threadIdx.x;
  int f = tid & (HID - 1);
  if (tid < NUM_PL * HID) {
    x[tid] = pl_emb[tid] + type_emb[f];
  } else {
    int idx = tid - NUM_PL * HID;
    if (idx < NUM_AR * HID)
      x[OFF_AR * HID + idx] = ar_emb[idx] + type_emb[2 * HID + f];
  }
}

// ---------------------------------------------------------------------------
// x[tr] = track_x @ W^T + b + type_emb[1]   (wave: 8 rows, lane = out feat)
// WS padded to stride 65: staging writes (k varies per lane) hit banks
// (k+j)%32 -> conflict-free (was 64-lanes-one-bank, 32-way).
// ---------------------------------------------------------------------------
__global__ __launch_bounds__(256) void k_track_lin(
    const float* __restrict__ tx, const float* __restrict__ W,
    const float* __restrict__ b, const float* __restrict__ type_emb,
    float* __restrict__ x) {
  __shared__ float WS[FEAT * 65];    // WS[k*65 + j] = W[j*128 + k]
  __shared__ float bs[HID];
  int t = threadIdx.x;
  for (int idx = t; idx < HID * FEAT; idx += 256) {
    int j = idx >> 7, k = idx & (FEAT - 1);
    WS[k * 65 + j] = W[idx];
  }
  if (t < HID) bs[t] = b[t] + type_emb[HID + t];
  __syncthreads();

  int j  = t & 63;
  int wv = __builtin_amdgcn_readfirstlane(t >> 6);
  int row0 = blockIdx.x * 32 + wv * 8;
  const float* xr = tx + (size_t)row0 * FEAT;

  float acc[8] = {0.f, 0.f, 0.f, 0.f, 0.f, 0.f, 0.f, 0.f};
#pragma unroll 4
  for (int k = 0; k < FEAT; ++k) {
    float w = WS[k * 65 + j];
#pragma unroll
    for (int r = 0; r < 8; ++r)
      acc[r] += xr[r * FEAT + k] * w;
  }
#pragma unroll
  for (int r = 0; r < 8; ++r)
    x[(OFF_TR + row0 + r) * HID + j] = acc[r] + bs[j];
}

// ---------------------------------------------------------------------------
// k_bin: each block takes BIN_CHUNK edges, groups them by dst bucket (d>>8)
// inside LDS, writes packed entries (d_off<<18 | s) to its OWN contiguous
// region pkd[e0 .. e0+cnt). tab[blk*TABW + b] = absolute slice start.
// ---------------------------------------------------------------------------
__global__ __launch_bounds__(256) void k_bin(
    const int* __restrict__ pls, const int* __restrict__ pld,
    const int* __restrict__ tas, const int* __restrict__ tad,
    int* __restrict__ pkd, int* __restrict__ tab) {
  __shared__ int hist[TABW];     // counts, then reused as write cursors
  __shared__ int offs[TABW];     // exclusive scan
  __shared__ int scanbuf[256];
  int t = threadIdx.x;
  int blk = blockIdx.x;
  int e0 = blk * BIN_CHUNK;
  int e1 = e0 + BIN_CHUNK; if (e1 > E_TOT) e1 = E_TOT;

  for (int i = t; i < TABW; i += 256) hist[i] = 0;
  __syncthreads();

  for (int e = e0 + t; e < e1; e += 256) {
    int s, d; edge_sd(e, pls, pld, tas, tad, s, d);
    int b = min(max(d >> 8, 0), NBUCK - 1);
    atomicAdd(&hist[b], 1);
  }
  __syncthreads();

  // exclusive scan of hist[0..624] -> offs[0..625]
  int i0 = 3 * t, i1 = 3 * t + 1, i2 = 3 * t + 2;
  int h0 = (i0 < NBUCK) ? hist[i0] : 0;
  int h1 = (i1 < NBUCK) ? hist[i1] : 0;
  int h2 = (i2 < NBUCK) ? hist[i2] : 0;
  int lsum = h0 + h1 + h2;
  scanbuf[t] = lsum;
  __syncthreads();
  int incl = lsum;
#pragma unroll
  for (int off = 1; off < 256; off <<= 1) {
    int add = (t >= off) ? scanbuf[t - off] : 0;
    __syncthreads();
    incl += add;
    scanbuf[t] = incl;
    __syncthreads();
  }
  int base = incl - lsum;
  if (i0 < TABW) offs[i0] = base;
  if (i1 < TABW) offs[i1] = base + h0;
  if (i2 < TABW) offs[i2] = base + h0 + h1;
  __syncthreads();

  for (int i = t; i < TABW; i += 256) tab[blk * TABW + i] = e0 + offs[i];
  for (int i = t; i < NBUCK; i += 256) hist[i] = offs[i];  // cursors
  __syncthreads();

  for (int e = e0 + t; e < e1; e += 256) {
    int s, d; edge_sd(e, pls, pld, tas, tad, s, d);
    int b = min(max(d >> 8, 0), NBUCK - 1);
    int pos = atomicAdd(&hist[b], 1);
    int idx = min(max(e0 + pos, 0), PKD_CAP - 1);   // clamp (no-op if correct)
    pkd[idx] = ((d & 255) << 18) | s;
  }
}

// ---------------------------------------------------------------------------
// k_btot: bucket b total edge count = sum over bin-blocks of slice sizes.
// ---------------------------------------------------------------------------
__global__ __launch_bounds__(256) void k_btot(
    const int* __restrict__ tab, int* __restrict__ btot) {
  int b = blockIdx.x * 256 + threadIdx.x;
  if (b >= NBUCK) return;
  int sum = 0;
#pragma unroll 8
  for (int blk = 0; blk < NBLK_BIN; ++blk)
    sum += tab[blk * TABW + b + 1] - tab[blk * TABW + b];
  btot[b] = sum;
}

// ---------------------------------------------------------------------------
// k_bscan: single block, exclusive scan of the 625 bucket totals in place
// ---------------------------------------------------------------------------
__global__ __launch_bounds__(1024) void k_bscan(int* __restrict__ btot) {
  __shared__ int s[1024];
  int t = threadIdx.x;
  int val = (t < NBUCK) ? btot[t] : 0;
  s[t] = val;
  __syncthreads();
  int incl = val;
#pragma unroll
  for (int off = 1; off < 1024; off <<= 1) {
    int add = (t >= off) ? s[t - off] : 0;
    __syncthreads();
    incl += add;
    s[t] = incl;
    __syncthreads();
  }
  if (t < NBUCK) btot[t] = incl - val;  // exclusive
}

// ---------------------------------------------------------------------------
// k_fill3: one WG per 256-node bucket.
// Pass 1: count per-node degrees in LDS, scan -> rowptr.
// Pass 2: write col densely via LDS cursors. No global atomics.
// ---------------------------------------------------------------------------
__global__ __launch_bounds__(256) void k_fill3(
    const int* __restrict__ tab, const int* __restrict__ pkd,
    const int* __restrict__ btot, int* __restrict__ rowptr,
    int* __restrict__ col) {
  __shared__ int cnt[256];       // counts, then absolute write cursors
  __shared__ int scanbuf[256];
  int t = threadIdx.x;
  int b = blockIdx.x;
  cnt[t] = 0;
  __syncthreads();

  // pass 1: per-node degree counts
  for (int blk = t; blk < NBLK_BIN; blk += 256) {
    int s0 = tab[blk * TABW + b];
    int s1 = tab[blk * TABW + b + 1];
    s0 = min(max(s0, 0), PKD_CAP);
    s1 = min(max(s1, s0), PKD_CAP);
    for (int i = s0; i < s1; ++i) {
      int doff = (pkd[i] >> 18) & 255;
      atomicAdd(&cnt[doff], 1);
    }
  }
  __syncthreads();

  // exclusive scan of cnt -> per-node offsets within the bucket
  int val = cnt[t];
  scanbuf[t] = val;
  __syncthreads();
  int incl = val;
#pragma unroll
  for (int off = 1; off < 256; off <<= 1) {
    int add = (t >= off) ? scanbuf[t - off] : 0;
    __syncthreads();
    incl += add;
    scanbuf[t] = incl;
    __syncthreads();
  }
  int rp = btot[b] + incl - val;     // absolute CSR row start
  rowptr[(b << 8) + t] = rp;
  if (b == NBUCK - 1 && t == 255) rowptr[NN] = E_TOT;
  __syncthreads();                   // all reads of cnt (val) done
  cnt[t] = rp;                       // cursor
  __syncthreads();

  // pass 2: fill col
  for (int blk = t; blk < NBLK_BIN; blk += 256) {
    int s0 = tab[blk * TABW + b];
    int s1 = tab[blk * TABW + b + 1];
    s0 = min(max(s0, 0), PKD_CAP);
    s1 = min(max(s1, s0), PKD_CAP);
    for (int i = s0; i < s1; ++i) {
      int pk = pkd[i];
      int doff = (pk >> 18) & 255;
      int pos = atomicAdd(&cnt[doff], 1);
      pos = min(max(pos, 0), E_TOT - 1);            // clamp (no-op if correct)
      col[pos] = pk & 0x3FFFF;
    }
  }
}

// ---------------------------------------------------------------------------
// gather one node's mean-aggregated row; result valid in ALL 64 lanes
// (lane holds float4 columns 4c..4c+3, c = lane&15).
// ---------------------------------------------------------------------------
__device__ __forceinline__ float4 gather_mean(
    const int* __restrict__ rowptr, const int* __restrict__ col,
    const float4* __restrict__ x4, int n, int r, int c) {
  int rp0 = rowptr[n], rp1 = rowptr[n + 1];
  float4 a0 = {0.f, 0.f, 0.f, 0.f};
  float4 a1 = {0.f, 0.f, 0.f, 0.f};
  float4 a2 = {0.f, 0.f, 0.f, 0.f};
  float4 a3 = {0.f, 0.f, 0.f, 0.f};
  int base = rp0;
  for (; base + 16 <= rp1; base += 16) {
    int s0 = col[base + r];
    int s1 = col[base + 4 + r];
    int s2 = col[base + 8 + r];
    int s3 = col[base + 12 + r];
    float4 v0 = x4[(size_t)s0 * 16 + c];
    float4 v1 = x4[(size_t)s1 * 16 + c];
    float4 v2 = x4[(size_t)s2 * 16 + c];
    float4 v3 = x4[(size_t)s3 * 16 + c];
    a0.x += v0.x; a0.y += v0.y; a0.z += v0.z; a0.w += v0.w;
    a1.x += v1.x; a1.y += v1.y; a1.z += v1.z; a1.w += v1.w;
    a2.x += v2.x; a2.y += v2.y; a2.z += v2.z; a2.w += v2.w;
    a3.x += v3.x; a3.y += v3.y; a3.z += v3.z; a3.w += v3.w;
  }
  if (base + 4 <= rp1) {
    int s0 = col[base + r];
    float4 v0 = x4[(size_t)s0 * 16 + c];
    a0.x += v0.x; a0.y += v0.y; a0.z += v0.z; a0.w += v0.w;
    base += 4;
  }
  if (base + 4 <= rp1) {
    int s1 = col[base + r];
    float4 v1 = x4[(size_t)s1 * 16 + c];
    a1.x += v1.x; a1.y += v1.y; a1.z += v1.z; a1.w += v1.w;
    base += 4;
  }
  if (base + 4 <= rp1) {
    int s2 = col[base + r];
    float4 v2 = x4[(size_t)s2 * 16 + c];
    a2.x += v2.x; a2.y += v2.y; a2.z += v2.z; a2.w += v2.w;
    base += 4;
  }
  if (base + r < rp1) {
    int s3 = col[base + r];
    float4 v3 = x4[(size_t)s3 * 16 + c];
    a3.x += v3.x; a3.y += v3.y; a3.z += v3.z; a3.w += v3.w;
  }
  float4 a;
  a.x = (a0.x + a1.x) + (a2.x + a3.x);
  a.y = (a0.y + a1.y) + (a2.y + a3.y);
  a.z = (a0.z + a1.z) + (a2.z + a3.z);
  a.w = (a0.w + a1.w) + (a2.w + a3.w);
  a.x += __shfl_xor(a.x, 16); a.y += __shfl_xor(a.y, 16);
  a.z += __shfl_xor(a.z, 16); a.w += __shfl_xor(a.w, 16);
  a.x += __shfl_xor(a.x, 32); a.y += __shfl_xor(a.y, 32);
  a.z += __shfl_xor(a.z, 32); a.w += __shfl_xor(a.w, 32);
  float id = 1.0f / (float)max(rp1 - rp0, 1);
  a.x *= id; a.y *= id; a.z *= id; a.w *= id;
  return a;
}

// ---------------------------------------------------------------------------
// FUSED gather + SAGE update:
//   xn[n] = relu( (mean_{s in N(n)} xo[s]) @ Wl^T + bl + xo[n] @ Wr^T )
// 512 threads = 8 waves; 4 nodes per wave, processed as 2 groups of 2.
// Weights in LDS row-major padded (stride 68): lane j reads its OWN row of
// Wl/Wr as aligned ds_read_b128 (4 elems/op, conflict-free); staging writes
// conflict-free (was the 3.97e7-cycle SQ_LDS_BANK_CONFLICT hotspot).
// Row/root broadcasts use v_readlane (compile-time lane) -- NO LDS traffic.
// ---------------------------------------------------------------------------
__global__ __launch_bounds__(512, 6) void k_gather_update(
    const int* __restrict__ rowptr, const int* __restrict__ col,
    const float* __restrict__ xo,
    const float* __restrict__ Wl, const float* __restrict__ bl,
    const float* __restrict__ Wr,
    float* __restrict__ xn) {
  __shared__ float WlS[HID * WSTRIDE];   // WlS[j*68 + k] = Wl[j*64 + k]
  __shared__ float WrS[HID * WSTRIDE];
  __shared__ float bs[HID];
  int t = threadIdx.x;
  for (int idx = t; idx < HID * HID; idx += 512) {
    int j = idx >> 6, k = idx & 63;
    WlS[j * WSTRIDE + k] = Wl[idx];
    WrS[j * WSTRIDE + k] = Wr[idx];
  }
  if (t < HID) bs[t] = bl[t];
  __syncthreads();

  int lane = t & 63;
  int wv = t >> 6;            // 0..7
  int r = lane >> 4;          // neighbor slot 0..3
  int c = lane & 15;          // float4 column 0..15
  const float4* x4 = (const float4*)xo;
  const float4* wl4 = (const float4*)&WlS[lane * WSTRIDE];
  const float4* wr4 = (const float4*)&WrS[lane * WSTRIDE];
  float bias = bs[lane];

  for (int g = 0; g < 2; ++g) {
    int n0 = (blockIdx.x * 8 + wv) * 4 + g * 2;
    int n1 = n0 + 1;

    // roots: all lanes load (same cache lines as r==0's load; keeps values
    // in every lane so v_readlane can source from lanes 0..15 safely)
    float4 root0 = x4[(size_t)n0 * 16 + c];
    float4 root1 = x4[(size_t)n1 * 16 + c];

    float4 res0 = gather_mean(rowptr, col, x4, n0, r, c);
    float4 res1 = gather_mean(rowptr, col, x4, n1, r, c);

    // update: lane = output feature j; acc_j = sum_k agg[k]*Wl[j][k] +
    // root[k]*Wr[j][k]. agg/root element 4*k4+m lives in lane k4, comp m.
    float a0A = 0.f, a0B = 0.f, a1A = 0.f, a1B = 0.f;
#pragma unroll
    for (int k4 = 0; k4 < 16; ++k4) {
      float4 wl = wl4[k4];
      float4 wr = wr4[k4];
      float g0x = rlane(res0.x, k4), g0y = rlane(res0.y, k4);
      float g0z = rlane(res0.z, k4), g0w = rlane(res0.w, k4);
      float r0x = rlane(root0.x, k4), r0y = rlane(root0.y, k4);
      float r0z = rlane(root0.z, k4), r0w = rlane(root0.w, k4);
      float p0 = g0x * wl.x + g0y * wl.y + g0z * wl.z + g0w * wl.w
               + r0x * wr.x + r0y * wr.y + r0z * wr.z + r0w * wr.w;
      float g1x = rlane(res1.x, k4), g1y = rlane(res1.y, k4);
      float g1z = rlane(res1.z, k4), g1w = rlane(res1.w, k4);
      float r1x = rlane(root1.x, k4), r1y = rlane(root1.y, k4);
      float r1z = rlane(root1.z, k4), r1w = rlane(root1.w, k4);
      float p1 = g1x * wl.x + g1y * wl.y + g1z * wl.z + g1w * wl.w
               + r1x * wr.x + r1y * wr.y + r1z * wr.z + r1w * wr.w;
      if (k4 & 1) { a0B += p0; a1B += p1; }
      else        { a0A += p0; a1A += p1; }
    }
    xn[(size_t)n0 * HID + lane] = fmaxf(a0A + a0B + bias, 0.f);
    xn[(size_t)n1 * HID + lane] = fmaxf(a1A + a1B + bias, 0.f);
  }
}

// ---------------------------------------------------------------------------
extern "C" void kernel_launch(void* const* d_in, const int* in_sizes, int n_in,
                              void* d_out, int out_size, void* d_ws, size_t ws_size,
                              hipStream_t stream) {
  const float* track_x  = (const float*)d_in[0];
  const int*   pl_tr_s  = (const int*)d_in[1];
  const int*   pl_tr_d  = (const int*)d_in[2];
  const int*   tr_ar_s  = (const int*)d_in[3];
  const int*   tr_ar_d  = (const int*)d_in[4];
  const float* pl_emb   = (const float*)d_in[5];
  const float* ar_emb   = (const float*)d_in[6];
  const float* track_W  = (const float*)d_in[7];
  const float* track_b  = (const float*)d_in[8];
  const float* type_emb = (const float*)d_in[9];
  const float* conv_Wl  = (const float*)d_in[10];
  const float* conv_bl  = (const float*)d_in[11];
  const float* conv_Wr  = (const float*)d_in[12];

  float* x = (float*)d_out;                      // node state (NN*64)

  // workspace: xalt ALIASES [pkd|tab] -- pkd/tab are dead once k_fill3 has
  // produced rowptr+col; xalt is first written by the layer-0 fused kernel
  // (stream-ordered after fill3). Total: 40.96 (xalt region, covers pkd
  // 16.81 + tab 1.29) + col 16.8 + rowptr 0.64 + btot 4KB = ~58.4 MB.
  char* w = (char*)d_ws;
  float* xalt   = (float*)w;
  int*   pkd    = (int*)w;
  int*   tab    = (int*)(w + (size_t)PKD_CAP * 4);
  w += (size_t)NN * HID * 4;
  int*   col    = (int*)w;    w += (size_t)E_TOT * 4;
  int*   rowptr = (int*)w;    w += (size_t)(NN + 1) * 4;
  int*   btot   = (int*)w;    // NBUCK ints

  k_init_emb<<<(NUM_PL + NUM_AR) * HID / 256, 256, 0, stream>>>(
      pl_emb, ar_emb, type_emb, x);
  k_track_lin<<<NUM_TR / 32, 256, 0, stream>>>(
      track_x, track_W, track_b, type_emb, x);

  // CSR build: bin -> bucket totals -> bucket scan -> count+scan+fill
  k_bin<<<NBLK_BIN, 256, 0, stream>>>(
      pl_tr_s, pl_tr_d, tr_ar_s, tr_ar_d, pkd, tab);
  k_btot<<<(NBUCK + 255) / 256, 256, 0, stream>>>(tab, btot);
  k_bscan<<<1, 1024, 0, stream>>>(btot);
  k_fill3<<<NBUCK, 256, 0, stream>>>(tab, pkd, btot, rowptr, col);

  // fused gather+update, ping-pong x <-> xalt (2 layers -> ends in x=d_out)
  k_gather_update<<<NN / 32, 512, 0, stream>>>(
      rowptr, col, x, conv_Wl, conv_bl, conv_Wr, xalt);
  k_gather_update<<<NN / 32, 512, 0, stream>>>(
      rowptr, col, xalt, conv_Wl + HID * HID, conv_bl + HID,
      conv_Wr + HID * HID, x);
}

// Round 6
// 766.980 us; speedup vs baseline: 2.4583x; 2.4583x over previous
//
#include <hip/hip_runtime.h>

#define NUM_PL 50000
#define NUM_TR 100000
#define NUM_AR 10000
#define NN     160000          // NUM_PL + NUM_TR + NUM_AR
#define HID    64
#define FEAT   128
#define E_PLTR 2000000
#define E_TRAR 100000
#define E_TOT  4200000         // 2*E_PLTR + 2*E_TRAR
#define OFF_TR 50000
#define OFF_AR 150000

#define BIN_CHUNK 8192
#define NBLK_BIN  513          // ceil(E_TOT / BIN_CHUNK)
#define NBUCK     625          // NN / 256 (exact)
#define TABW      626          // NBUCK + 1
#define PKD_CAP   (NBLK_BIN * BIN_CHUNK)

#define WSTR 65                // 64+1 padded stride: staging writes hit banks
                               // (lane+j)%32, update reads (k+lane)%32 - both
                               // free 2-way (was 32-way on staging writes)

// edge id -> (src,dst) global node ids, matching the reference concatenation
__device__ __forceinline__ void edge_sd(
    int e, const int* __restrict__ pls, const int* __restrict__ pld,
    const int* __restrict__ tas, const int* __restrict__ tad, int& s, int& d) {
  if (e < E_PLTR)                   { s = pls[e];               d = pld[e] + OFF_TR; }
  else if (e < 2 * E_PLTR)          { int i = e - E_PLTR;
                                      s = pld[i] + OFF_TR;      d = pls[i]; }
  else if (e < 2 * E_PLTR + E_TRAR) { int i = e - 2 * E_PLTR;
                                      s = tas[i] + OFF_TR;      d = tad[i] + OFF_AR; }
  else                              { int i = e - 2 * E_PLTR - E_TRAR;
                                      s = tad[i] + OFF_AR;      d = tas[i] + OFF_TR; }
}

// ---------------------------------------------------------------------------
// x[pl] = playlist_emb + type_emb[0];  x[ar] = artist_emb + type_emb[2]
// ---------------------------------------------------------------------------
__global__ __launch_bounds__(256) void k_init_emb(
    const float* __restrict__ pl_emb, const float* __restrict__ ar_emb,
    const float* __restrict__ type_emb, float* __restrict__ x) {
  int tid = blockIdx.x * 256 + threadIdx.x;
  int f = tid & (HID - 1);
  if (tid < NUM_PL * HID) {
    x[tid] = pl_emb[tid] + type_emb[f];
  } else {
    int idx = tid - NUM_PL * HID;
    if (idx < NUM_AR * HID)
      x[OFF_AR * HID + idx] = ar_emb[idx] + type_emb[2 * HID + f];
  }
}

// ---------------------------------------------------------------------------
// x[tr] = track_x @ W^T + b + type_emb[1]   (wave: 8 rows, lane = out feat)
// WS padded to stride 65: staging writes conflict-free (proven in R3 pass).
// ---------------------------------------------------------------------------
__global__ __launch_bounds__(256) void k_track_lin(
    const float* __restrict__ tx, const float* __restrict__ W,
    const float* __restrict__ b, const float* __restrict__ type_emb,
    float* __restrict__ x) {
  __shared__ float WS[FEAT * 65];    // WS[k*65 + j] = W[j*128 + k]
  __shared__ float bs[HID];
  int t = threadIdx.x;
  for (int idx = t; idx < HID * FEAT; idx += 256) {
    int j = idx >> 7, k = idx & (FEAT - 1);
    WS[k * 65 + j] = W[idx];
  }
  if (t < HID) bs[t] = b[t] + type_emb[HID + t];
  __syncthreads();

  int j  = t & 63;
  int wv = __builtin_amdgcn_readfirstlane(t >> 6);
  int row0 = blockIdx.x * 32 + wv * 8;
  const float* xr = tx + (size_t)row0 * FEAT;

  float acc[8] = {0.f, 0.f, 0.f, 0.f, 0.f, 0.f, 0.f, 0.f};
#pragma unroll 4
  for (int k = 0; k < FEAT; ++k) {
    float w = WS[k * 65 + j];
#pragma unroll
    for (int r = 0; r < 8; ++r)
      acc[r] += xr[r * FEAT + k] * w;
  }
#pragma unroll
  for (int r = 0; r < 8; ++r)
    x[(OFF_TR + row0 + r) * HID + j] = acc[r] + bs[j];
}

// ---------------------------------------------------------------------------
// k_bin: each block takes BIN_CHUNK edges, groups them by dst bucket (d>>8)
// inside LDS, writes packed entries (d_off<<18 | s) to its OWN contiguous
// region pkd[e0 .. e0+cnt). tab[blk*TABW + b] = absolute slice start.
// ---------------------------------------------------------------------------
__global__ __launch_bounds__(256) void k_bin(
    const int* __restrict__ pls, const int* __restrict__ pld,
    const int* __restrict__ tas, const int* __restrict__ tad,
    int* __restrict__ pkd, int* __restrict__ tab) {
  __shared__ int hist[TABW];     // counts, then reused as write cursors
  __shared__ int offs[TABW];     // exclusive scan
  __shared__ int scanbuf[256];
  int t = threadIdx.x;
  int blk = blockIdx.x;
  int e0 = blk * BIN_CHUNK;
  int e1 = e0 + BIN_CHUNK; if (e1 > E_TOT) e1 = E_TOT;

  for (int i = t; i < TABW; i += 256) hist[i] = 0;
  __syncthreads();

  for (int e = e0 + t; e < e1; e += 256) {
    int s, d; edge_sd(e, pls, pld, tas, tad, s, d);
    int b = min(max(d >> 8, 0), NBUCK - 1);
    atomicAdd(&hist[b], 1);
  }
  __syncthreads();

  // exclusive scan of hist[0..624] -> offs[0..625]
  int i0 = 3 * t, i1 = 3 * t + 1, i2 = 3 * t + 2;
  int h0 = (i0 < NBUCK) ? hist[i0] : 0;
  int h1 = (i1 < NBUCK) ? hist[i1] : 0;
  int h2 = (i2 < NBUCK) ? hist[i2] : 0;
  int lsum = h0 + h1 + h2;
  scanbuf[t] = lsum;
  __syncthreads();
  int incl = lsum;
#pragma unroll
  for (int off = 1; off < 256; off <<= 1) {
    int add = (t >= off) ? scanbuf[t - off] : 0;
    __syncthreads();
    incl += add;
    scanbuf[t] = incl;
    __syncthreads();
  }
  int base = incl - lsum;
  if (i0 < TABW) offs[i0] = base;
  if (i1 < TABW) offs[i1] = base + h0;
  if (i2 < TABW) offs[i2] = base + h0 + h1;
  __syncthreads();

  for (int i = t; i < TABW; i += 256) tab[blk * TABW + i] = e0 + offs[i];
  for (int i = t; i < NBUCK; i += 256) hist[i] = offs[i];  // cursors
  __syncthreads();

  for (int e = e0 + t; e < e1; e += 256) {
    int s, d; edge_sd(e, pls, pld, tas, tad, s, d);
    int b = min(max(d >> 8, 0), NBUCK - 1);
    int pos = atomicAdd(&hist[b], 1);
    int idx = min(max(e0 + pos, 0), PKD_CAP - 1);   // clamp (no-op if correct)
    pkd[idx] = ((d & 255) << 18) | s;
  }
}

// ---------------------------------------------------------------------------
// k_btot: bucket b total edge count = sum over bin-blocks of slice sizes.
// ---------------------------------------------------------------------------
__global__ __launch_bounds__(256) void k_btot(
    const int* __restrict__ tab, int* __restrict__ btot) {
  int b = blockIdx.x * 256 + threadIdx.x;
  if (b >= NBUCK) return;
  int sum = 0;
#pragma unroll 8
  for (int blk = 0; blk < NBLK_BIN; ++blk)
    sum += tab[blk * TABW + b + 1] - tab[blk * TABW + b];
  btot[b] = sum;
}

// ---------------------------------------------------------------------------
// k_bscan: single block, exclusive scan of the 625 bucket totals in place
// ---------------------------------------------------------------------------
__global__ __launch_bounds__(1024) void k_bscan(int* __restrict__ btot) {
  __shared__ int s[1024];
  int t = threadIdx.x;
  int val = (t < NBUCK) ? btot[t] : 0;
  s[t] = val;
  __syncthreads();
  int incl = val;
#pragma unroll
  for (int off = 1; off < 1024; off <<= 1) {
    int add = (t >= off) ? s[t - off] : 0;
    __syncthreads();
    incl += add;
    s[t] = incl;
    __syncthreads();
  }
  if (t < NBUCK) btot[t] = incl - val;  // exclusive
}

// ---------------------------------------------------------------------------
// k_fill3: one WG per 256-node bucket.
// Pass 1: count per-node degrees in LDS, scan -> rowptr.
// Pass 2: write col densely via LDS cursors. No global atomics.
// ---------------------------------------------------------------------------
__global__ __launch_bounds__(256) void k_fill3(
    const int* __restrict__ tab, const int* __restrict__ pkd,
    const int* __restrict__ btot, int* __restrict__ rowptr,
    int* __restrict__ col) {
  __shared__ int cnt[256];       // counts, then absolute write cursors
  __shared__ int scanbuf[256];
  int t = threadIdx.x;
  int b = blockIdx.x;
  cnt[t] = 0;
  __syncthreads();

  // pass 1: per-node degree counts
  for (int blk = t; blk < NBLK_BIN; blk += 256) {
    int s0 = tab[blk * TABW + b];
    int s1 = tab[blk * TABW + b + 1];
    s0 = min(max(s0, 0), PKD_CAP);
    s1 = min(max(s1, s0), PKD_CAP);
    for (int i = s0; i < s1; ++i) {
      int doff = (pkd[i] >> 18) & 255;
      atomicAdd(&cnt[doff], 1);
    }
  }
  __syncthreads();

  // exclusive scan of cnt -> per-node offsets within the bucket
  int val = cnt[t];
  scanbuf[t] = val;
  __syncthreads();
  int incl = val;
#pragma unroll
  for (int off = 1; off < 256; off <<= 1) {
    int add = (t >= off) ? scanbuf[t - off] : 0;
    __syncthreads();
    incl += add;
    scanbuf[t] = incl;
    __syncthreads();
  }
  int rp = btot[b] + incl - val;     // absolute CSR row start
  rowptr[(b << 8) + t] = rp;
  if (b == NBUCK - 1 && t == 255) rowptr[NN] = E_TOT;
  __syncthreads();                   // all reads of cnt (val) done
  cnt[t] = rp;                       // cursor
  __syncthreads();

  // pass 2: fill col
  for (int blk = t; blk < NBLK_BIN; blk += 256) {
    int s0 = tab[blk * TABW + b];
    int s1 = tab[blk * TABW + b + 1];
    s0 = min(max(s0, 0), PKD_CAP);
    s1 = min(max(s1, s0), PKD_CAP);
    for (int i = s0; i < s1; ++i) {
      int pk = pkd[i];
      int doff = (pk >> 18) & 255;
      int pos = atomicAdd(&cnt[doff], 1);
      pos = min(max(pos, 0), E_TOT - 1);            // clamp (no-op if correct)
      col[pos] = pk & 0x3FFFF;
    }
  }
}

// ---------------------------------------------------------------------------
// FUSED gather + SAGE update (R2 structure EXACTLY, two minimal changes):
//   xn[n] = relu( (mean_{s in N(n)} xo[s]) @ Wl^T + bl + xo[n] @ Wr^T )
// 512 threads = 8 waves; 4 nodes per wave. Per node: wave gathers into
// registers (16 edges/iter), shfl-reduces, parks the mean'd agg row + root
// row in a WAVE-PRIVATE 512B LDS slot, then lane j computes output feature
// j via scalar broadcasts myrow[k] (uniform addr) and WlS/WrS reads.
// Change 1 (perf): weight LDS stride 64 -> 65. Staging write banks go from
//   all-64-lanes-on-one-bank (measured SQ_LDS_BANK_CONFLICT = 3.97e7) to
//   (lane+j)%32 = free 2-way; update reads (k+lane)%32 = free 2-way.
// Change 2 (safety): explicit s_waitcnt lgkmcnt(0) + sched_barrier between
//   the park-write and the broadcast reads. R4's vectorized park reads
//   produced replay-nondeterministic results (a write->read ordering race
//   under compiler scheduling); this pins the order at the pipe level.
// ---------------------------------------------------------------------------
__global__ __launch_bounds__(512, 8) void k_gather_update(
    const int* __restrict__ rowptr, const int* __restrict__ col,
    const float* __restrict__ xo,
    const float* __restrict__ Wl, const float* __restrict__ bl,
    const float* __restrict__ Wr,
    float* __restrict__ xn) {
  __shared__ float WlS[HID * WSTR];   // WlS[k*65+j] = Wl[j*64+k]
  __shared__ float WrS[HID * WSTR];
  __shared__ float bs[HID];
  __shared__ __align__(16) float rowS[8][2 * HID];  // per wave: agg | root
  int t = threadIdx.x;
  for (int idx = t; idx < HID * HID; idx += 512) {
    int j = idx >> 6, k = idx & 63;
    WlS[k * WSTR + j] = Wl[idx];
    WrS[k * WSTR + j] = Wr[idx];
  }
  if (t < HID) bs[t] = bl[t];
  __syncthreads();

  int lane = t & 63;
  int wv = t >> 6;            // 0..7
  int r = lane >> 4;          // neighbor slot 0..3
  int c = lane & 15;          // float4 column 0..15
  const float4* x4 = (const float4*)xo;
  float* myrow = &rowS[wv][0];

  for (int it = 0; it < 4; ++it) {
    int n = (blockIdx.x * 8 + wv) * 4 + it;
    int rp0 = rowptr[n], rp1 = rowptr[n + 1];

    // root row: issue early so latency hides under the gather
    float4 root;
    if (r == 0) root = x4[(size_t)n * 16 + c];

    float4 a0 = {0.f, 0.f, 0.f, 0.f};
    float4 a1 = {0.f, 0.f, 0.f, 0.f};
    float4 a2 = {0.f, 0.f, 0.f, 0.f};
    float4 a3 = {0.f, 0.f, 0.f, 0.f};
    int base = rp0;
    for (; base + 16 <= rp1; base += 16) {
      int s0 = col[base + r];
      int s1 = col[base + 4 + r];
      int s2 = col[base + 8 + r];
      int s3 = col[base + 12 + r];
      float4 v0 = x4[(size_t)s0 * 16 + c];
      float4 v1 = x4[(size_t)s1 * 16 + c];
      float4 v2 = x4[(size_t)s2 * 16 + c];
      float4 v3 = x4[(size_t)s3 * 16 + c];
      a0.x += v0.x; a0.y += v0.y; a0.z += v0.z; a0.w += v0.w;
      a1.x += v1.x; a1.y += v1.y; a1.z += v1.z; a1.w += v1.w;
      a2.x += v2.x; a2.y += v2.y; a2.z += v2.z; a2.w += v2.w;
      a3.x += v3.x; a3.y += v3.y; a3.z += v3.z; a3.w += v3.w;
    }
    if (base + 4 <= rp1) {
      int s0 = col[base + r];
      float4 v0 = x4[(size_t)s0 * 16 + c];
      a0.x += v0.x; a0.y += v0.y; a0.z += v0.z; a0.w += v0.w;
      base += 4;
    }
    if (base + 4 <= rp1) {
      int s1 = col[base + r];
      float4 v1 = x4[(size_t)s1 * 16 + c];
      a1.x += v1.x; a1.y += v1.y; a1.z += v1.z; a1.w += v1.w;
      base += 4;
    }
    if (base + 4 <= rp1) {
      int s2 = col[base + r];
      float4 v2 = x4[(size_t)s2 * 16 + c];
      a2.x += v2.x; a2.y += v2.y; a2.z += v2.z; a2.w += v2.w;
      base += 4;
    }
    if (base + r < rp1) {
      int s3 = col[base + r];
      float4 v3 = x4[(size_t)s3 * 16 + c];
      a3.x += v3.x; a3.y += v3.y; a3.z += v3.z; a3.w += v3.w;
    }
    float4 a;
    a.x = (a0.x + a1.x) + (a2.x + a3.x);
    a.y = (a0.y + a1.y) + (a2.y + a3.y);
    a.z = (a0.z + a1.z) + (a2.z + a3.z);
    a.w = (a0.w + a1.w) + (a2.w + a3.w);
    a.x += __shfl_xor(a.x, 16); a.y += __shfl_xor(a.y, 16);
    a.z += __shfl_xor(a.z, 16); a.w += __shfl_xor(a.w, 16);
    a.x += __shfl_xor(a.x, 32); a.y += __shfl_xor(a.y, 32);
    a.z += __shfl_xor(a.z, 32); a.w += __shfl_xor(a.w, 32);

    // park mean'd agg row + root row in wave-private LDS
    if (r == 0) {
      float id = 1.0f / (float)max(rp1 - rp0, 1);
      float4 o;
      o.x = a.x * id; o.y = a.y * id; o.z = a.z * id; o.w = a.w * id;
      ((float4*)myrow)[c] = o;
      ((float4*)myrow)[16 + c] = root;
    }
    // pin write->read order at the DS pipe level (replay-race hedge)
    asm volatile("s_waitcnt lgkmcnt(0)" ::: "memory");
    __builtin_amdgcn_sched_barrier(0);

    // update: lane = output feature j (scalar broadcasts, R2-proven path)
    float acc = 0.f;
#pragma unroll 8
    for (int k = 0; k < HID; ++k) {
      acc += myrow[k] * WlS[k * WSTR + lane]
           + myrow[HID + k] * WrS[k * WSTR + lane];
    }
    xn[(size_t)n * HID + lane] = fmaxf(acc + bs[lane], 0.f);
  }
}

// ---------------------------------------------------------------------------
extern "C" void kernel_launch(void* const* d_in, const int* in_sizes, int n_in,
                              void* d_out, int out_size, void* d_ws, size_t ws_size,
                              hipStream_t stream) {
  const float* track_x  = (const float*)d_in[0];
  const int*   pl_tr_s  = (const int*)d_in[1];
  const int*   pl_tr_d  = (const int*)d_in[2];
  const int*   tr_ar_s  = (const int*)d_in[3];
  const int*   tr_ar_d  = (const int*)d_in[4];
  const float* pl_emb   = (const float*)d_in[5];
  const float* ar_emb   = (const float*)d_in[6];
  const float* track_W  = (const float*)d_in[7];
  const float* track_b  = (const float*)d_in[8];
  const float* type_emb = (const float*)d_in[9];
  const float* conv_Wl  = (const float*)d_in[10];
  const float* conv_bl  = (const float*)d_in[11];
  const float* conv_Wr  = (const float*)d_in[12];

  float* x = (float*)d_out;                      // node state (NN*64)

  // workspace: xalt ALIASES [pkd|tab] -- pkd/tab are dead once k_fill3 has
  // produced rowptr+col; xalt is first written by the layer-0 fused kernel
  // (stream-ordered after fill3). Total: 40.96 (xalt region, covers pkd
  // 16.81 + tab 1.29) + col 16.8 + rowptr 0.64 + btot 4KB = ~58.4 MB.
  char* w = (char*)d_ws;
  float* xalt   = (float*)w;
  int*   pkd    = (int*)w;
  int*   tab    = (int*)(w + (size_t)PKD_CAP * 4);
  w += (size_t)NN * HID * 4;
  int*   col    = (int*)w;    w += (size_t)E_TOT * 4;
  int*   rowptr = (int*)w;    w += (size_t)(NN + 1) * 4;
  int*   btot   = (int*)w;    // NBUCK ints

  k_init_emb<<<(NUM_PL + NUM_AR) * HID / 256, 256, 0, stream>>>(
      pl_emb, ar_emb, type_emb, x);
  k_track_lin<<<NUM_TR / 32, 256, 0, stream>>>(
      track_x, track_W, track_b, type_emb, x);

  // CSR build: bin -> bucket totals -> bucket scan -> count+scan+fill
  k_bin<<<NBLK_BIN, 256, 0, stream>>>(
      pl_tr_s, pl_tr_d, tr_ar_s, tr_ar_d, pkd, tab);
  k_btot<<<(NBUCK + 255) / 256, 256, 0, stream>>>(tab, btot);
  k_bscan<<<1, 1024, 0, stream>>>(btot);
  k_fill3<<<NBUCK, 256, 0, stream>>>(tab, pkd, btot, rowptr, col);

  // fused gather+update, ping-pong x <-> xalt (2 layers -> ends in x=d_out)
  k_gather_update<<<NN / 32, 512, 0, stream>>>(
      rowptr, col, x, conv_Wl, conv_bl, conv_Wr, xalt);
  k_gather_update<<<NN / 32, 512, 0, stream>>>(
      rowptr, col, xalt, conv_Wl + HID * HID, conv_bl + HID,
      conv_Wr + HID * HID, x);
}

// Round 8
// 750.044 us; speedup vs baseline: 2.5138x; 1.0226x over previous
//
#include <hip/hip_runtime.h>

#define NUM_PL 50000
#define NUM_TR 100000
#define NUM_AR 10000
#define NN     160000          // NUM_PL + NUM_TR + NUM_AR
#define HID    64
#define FEAT   128
#define E_PLTR 2000000
#define E_TRAR 100000
#define E_TOT  4200000         // 2*E_PLTR + 2*E_TRAR
#define OFF_TR 50000
#define OFF_AR 150000

#define BIN_CHUNK 8192
#define NBLK_BIN  513          // ceil(E_TOT / BIN_CHUNK)
#define NBUCK     625          // NN / 256 (exact)
#define TABW      626          // NBUCK + 1
#define PKD_CAP   (NBLK_BIN * BIN_CHUNK)

#define WSTR 65                // 64+1 padded stride: staging writes hit banks
                               // (lane+j)%32, update reads (k+lane)%32 - both
                               // free 2-way (was 32-way on staging writes)

// edge id -> (src,dst) global node ids, matching the reference concatenation
__device__ __forceinline__ void edge_sd(
    int e, const int* __restrict__ pls, const int* __restrict__ pld,
    const int* __restrict__ tas, const int* __restrict__ tad, int& s, int& d) {
  if (e < E_PLTR)                   { s = pls[e];               d = pld[e] + OFF_TR; }
  else if (e < 2 * E_PLTR)          { int i = e - E_PLTR;
                                      s = pld[i] + OFF_TR;      d = pls[i]; }
  else if (e < 2 * E_PLTR + E_TRAR) { int i = e - 2 * E_PLTR;
                                      s = tas[i] + OFF_TR;      d = tad[i] + OFF_AR; }
  else                              { int i = e - 2 * E_PLTR - E_TRAR;
                                      s = tad[i] + OFF_AR;      d = tas[i] + OFF_TR; }
}

// ---------------------------------------------------------------------------
// x[pl] = playlist_emb + type_emb[0];  x[ar] = artist_emb + type_emb[2]
// ---------------------------------------------------------------------------
__global__ __launch_bounds__(256) void k_init_emb(
    const float* __restrict__ pl_emb, const float* __restrict__ ar_emb,
    const float* __restrict__ type_emb, float* __restrict__ x) {
  int tid = blockIdx.x * 256 + threadIdx.x;
  int f = tid & (HID - 1);
  if (tid < NUM_PL * HID) {
    x[tid] = pl_emb[tid] + type_emb[f];
  } else {
    int idx = tid - NUM_PL * HID;
    if (idx < NUM_AR * HID)
      x[OFF_AR * HID + idx] = ar_emb[idx] + type_emb[2 * HID + f];
  }
}

// ---------------------------------------------------------------------------
// x[tr] = track_x @ W^T + b + type_emb[1]   (wave: 8 rows, lane = out feat)
// WS padded to stride 65: staging writes conflict-free.
// ---------------------------------------------------------------------------
__global__ __launch_bounds__(256) void k_track_lin(
    const float* __restrict__ tx, const float* __restrict__ W,
    const float* __restrict__ b, const float* __restrict__ type_emb,
    float* __restrict__ x) {
  __shared__ float WS[FEAT * 65];    // WS[k*65 + j] = W[j*128 + k]
  __shared__ float bs[HID];
  int t = threadIdx.x;
  for (int idx = t; idx < HID * FEAT; idx += 256) {
    int j = idx >> 7, k = idx & (FEAT - 1);
    WS[k * 65 + j] = W[idx];
  }
  if (t < HID) bs[t] = b[t] + type_emb[HID + t];
  __syncthreads();

  int j  = t & 63;
  int wv = __builtin_amdgcn_readfirstlane(t >> 6);
  int row0 = blockIdx.x * 32 + wv * 8;
  const float* xr = tx + (size_t)row0 * FEAT;

  float acc[8] = {0.f, 0.f, 0.f, 0.f, 0.f, 0.f, 0.f, 0.f};
#pragma unroll 4
  for (int k = 0; k < FEAT; ++k) {
    float w = WS[k * 65 + j];
#pragma unroll
    for (int r = 0; r < 8; ++r)
      acc[r] += xr[r * FEAT + k] * w;
  }
#pragma unroll
  for (int r = 0; r < 8; ++r)
    x[(OFF_TR + row0 + r) * HID + j] = acc[r] + bs[j];
}

// ---------------------------------------------------------------------------
// k_bin: each block takes BIN_CHUNK edges, groups them by dst bucket (d>>8)
// inside LDS, writes packed entries (d_off<<18 | s) to its OWN contiguous
// region pkd[e0 .. e0+cnt). tab[blk*TABW + b] = absolute slice start.
// ---------------------------------------------------------------------------
__global__ __launch_bounds__(256) void k_bin(
    const int* __restrict__ pls, const int* __restrict__ pld,
    const int* __restrict__ tas, const int* __restrict__ tad,
    int* __restrict__ pkd, int* __restrict__ tab) {
  __shared__ int hist[TABW];     // counts, then reused as write cursors
  __shared__ int offs[TABW];     // exclusive scan
  __shared__ int scanbuf[256];
  int t = threadIdx.x;
  int blk = blockIdx.x;
  int e0 = blk * BIN_CHUNK;
  int e1 = e0 + BIN_CHUNK; if (e1 > E_TOT) e1 = E_TOT;

  for (int i = t; i < TABW; i += 256) hist[i] = 0;
  __syncthreads();

  for (int e = e0 + t; e < e1; e += 256) {
    int s, d; edge_sd(e, pls, pld, tas, tad, s, d);
    int b = min(max(d >> 8, 0), NBUCK - 1);
    atomicAdd(&hist[b], 1);
  }
  __syncthreads();

  // exclusive scan of hist[0..624] -> offs[0..625]
  int i0 = 3 * t, i1 = 3 * t + 1, i2 = 3 * t + 2;
  int h0 = (i0 < NBUCK) ? hist[i0] : 0;
  int h1 = (i1 < NBUCK) ? hist[i1] : 0;
  int h2 = (i2 < NBUCK) ? hist[i2] : 0;
  int lsum = h0 + h1 + h2;
  scanbuf[t] = lsum;
  __syncthreads();
  int incl = lsum;
#pragma unroll
  for (int off = 1; off < 256; off <<= 1) {
    int add = (t >= off) ? scanbuf[t - off] : 0;
    __syncthreads();
    incl += add;
    scanbuf[t] = incl;
    __syncthreads();
  }
  int base = incl - lsum;
  if (i0 < TABW) offs[i0] = base;
  if (i1 < TABW) offs[i1] = base + h0;
  if (i2 < TABW) offs[i2] = base + h0 + h1;
  __syncthreads();

  for (int i = t; i < TABW; i += 256) tab[blk * TABW + i] = e0 + offs[i];
  for (int i = t; i < NBUCK; i += 256) hist[i] = offs[i];  // cursors
  __syncthreads();

  for (int e = e0 + t; e < e1; e += 256) {
    int s, d; edge_sd(e, pls, pld, tas, tad, s, d);
    int b = min(max(d >> 8, 0), NBUCK - 1);
    int pos = atomicAdd(&hist[b], 1);
    int idx = min(max(e0 + pos, 0), PKD_CAP - 1);   // clamp (no-op if correct)
    pkd[idx] = ((d & 255) << 18) | s;
  }
}

// ---------------------------------------------------------------------------
// k_btot: bucket b total edge count = sum over bin-blocks of slice sizes.
// ---------------------------------------------------------------------------
__global__ __launch_bounds__(256) void k_btot(
    const int* __restrict__ tab, int* __restrict__ btot) {
  int b = blockIdx.x * 256 + threadIdx.x;
  if (b >= NBUCK) return;
  int sum = 0;
#pragma unroll 8
  for (int blk = 0; blk < NBLK_BIN; ++blk)
    sum += tab[blk * TABW + b + 1] - tab[blk * TABW + b];
  btot[b] = sum;
}

// ---------------------------------------------------------------------------
// k_bscan: single block, exclusive scan of the 625 bucket totals in place
// ---------------------------------------------------------------------------
__global__ __launch_bounds__(1024) void k_bscan(int* __restrict__ btot) {
  __shared__ int s[1024];
  int t = threadIdx.x;
  int val = (t < NBUCK) ? btot[t] : 0;
  s[t] = val;
  __syncthreads();
  int incl = val;
#pragma unroll
  for (int off = 1; off < 1024; off <<= 1) {
    int add = (t >= off) ? s[t - off] : 0;
    __syncthreads();
    incl += add;
    s[t] = incl;
    __syncthreads();
  }
  if (t < NBUCK) btot[t] = incl - val;  // exclusive
}

// ---------------------------------------------------------------------------
// k_fill3: one WG per 256-node bucket.
// Pass 1: count per-node degrees in LDS, scan -> rowptr.
// Pass 2: write col densely via LDS cursors. No global atomics.
// ---------------------------------------------------------------------------
__global__ __launch_bounds__(256) void k_fill3(
    const int* __restrict__ tab, const int* __restrict__ pkd,
    const int* __restrict__ btot, int* __restrict__ rowptr,
    int* __restrict__ col) {
  __shared__ int cnt[256];       // counts, then absolute write cursors
  __shared__ int scanbuf[256];
  int t = threadIdx.x;
  int b = blockIdx.x;
  cnt[t] = 0;
  __syncthreads();

  // pass 1: per-node degree counts
  for (int blk = t; blk < NBLK_BIN; blk += 256) {
    int s0 = tab[blk * TABW + b];
    int s1 = tab[blk * TABW + b + 1];
    s0 = min(max(s0, 0), PKD_CAP);
    s1 = min(max(s1, s0), PKD_CAP);
    for (int i = s0; i < s1; ++i) {
      int doff = (pkd[i] >> 18) & 255;
      atomicAdd(&cnt[doff], 1);
    }
  }
  __syncthreads();

  // exclusive scan of cnt -> per-node offsets within the bucket
  int val = cnt[t];
  scanbuf[t] = val;
  __syncthreads();
  int incl = val;
#pragma unroll
  for (int off = 1; off < 256; off <<= 1) {
    int add = (t >= off) ? scanbuf[t - off] : 0;
    __syncthreads();
    incl += add;
    scanbuf[t] = incl;
    __syncthreads();
  }
  int rp = btot[b] + incl - val;     // absolute CSR row start
  rowptr[(b << 8) + t] = rp;
  if (b == NBUCK - 1 && t == 255) rowptr[NN] = E_TOT;
  __syncthreads();                   // all reads of cnt (val) done
  cnt[t] = rp;                       // cursor
  __syncthreads();

  // pass 2: fill col
  for (int blk = t; blk < NBLK_BIN; blk += 256) {
    int s0 = tab[blk * TABW + b];
    int s1 = tab[blk * TABW + b + 1];
    s0 = min(max(s0, 0), PKD_CAP);
    s1 = min(max(s1, s0), PKD_CAP);
    for (int i = s0; i < s1; ++i) {
      int pk = pkd[i];
      int doff = (pk >> 18) & 255;
      int pos = atomicAdd(&cnt[doff], 1);
      pos = min(max(pos, 0), E_TOT - 1);            // clamp (no-op if correct)
      col[pos] = pk & 0x3FFFF;
    }
  }
}

// ---------------------------------------------------------------------------
// FUSED gather + SAGE update, 4-node-batched (R6-proven base):
//   xn[n] = relu( (mean_{s in N(n)} xo[s]) @ Wl^T + bl + xo[n] @ Wr^T )
// 512 threads = 8 waves; 4 nodes per wave.
// Phase 1: gather all 4 nodes (16 edges/iter, 32-bit addressing), shfl-
//   reduce, park each mean'd agg row + root row in a WAVE-PRIVATE LDS slot.
// Fence: one s_waitcnt lgkmcnt(0) + sched_barrier before any park read
//   (R6-proven ordering discipline; parks are same-wave DS writes).
// Phase 2: batched update -- per k-quad, 8 uniform float4 row broadcasts +
//   8 per-lane weight scalars feed FOUR accumulators: ds_reads per node
//   drop 256 -> 64 (weights amortized 4x, broadcasts vectorized 4x).
//   Weight LDS stride 65: staging writes (lane+j)%32, reads (k+lane)%32,
//   both free 2-way (bank-conflict counter = 0 in R6).
// __launch_bounds__(512,6): VGPR cap ~85 avoids R3-style scratch spills;
//   observed occupancy was already 24 waves/CU and LDS (~50KB) sustains it.
// ---------------------------------------------------------------------------
__global__ __launch_bounds__(512, 6) void k_gather_update(
    const int* __restrict__ rowptr, const int* __restrict__ col,
    const float* __restrict__ xo,
    const float* __restrict__ Wl, const float* __restrict__ bl,
    const float* __restrict__ Wr,
    float* __restrict__ xn) {
  __shared__ float WlS[HID * WSTR];   // WlS[k*65+j] = Wl[j*64+k]
  __shared__ float WrS[HID * WSTR];
  __shared__ float bs[HID];
  __shared__ __align__(16) float rowS[8][4][2 * HID];  // wave, node: agg|root
  int t = threadIdx.x;
  for (int idx = t; idx < HID * HID; idx += 512) {
    int j = idx >> 6, k = idx & 63;
    WlS[k * WSTR + j] = Wl[idx];
    WrS[k * WSTR + j] = Wr[idx];
  }
  if (t < HID) bs[t] = bl[t];
  __syncthreads();

  int lane = t & 63;
  int wv = t >> 6;            // 0..7
  int r = lane >> 4;          // neighbor slot 0..3
  int c = lane & 15;          // float4 column 0..15
  const float4* x4 = (const float4*)xo;
  int nbase = (blockIdx.x * 8 + wv) * 4;

  // ---- phase 1: gather 4 nodes, park rows ----
  for (int it = 0; it < 4; ++it) {
    int n = nbase + it;
    int rp0 = rowptr[n], rp1 = rowptr[n + 1];

    // root row: issue early so latency hides under the gather
    float4 root;
    if (r == 0) root = x4[n * 16 + c];

    float4 a0 = {0.f, 0.f, 0.f, 0.f};
    float4 a1 = {0.f, 0.f, 0.f, 0.f};
    float4 a2 = {0.f, 0.f, 0.f, 0.f};
    float4 a3 = {0.f, 0.f, 0.f, 0.f};
    int base = rp0;
    for (; base + 16 <= rp1; base += 16) {
      int s0 = col[base + r];
      int s1 = col[base + 4 + r];
      int s2 = col[base + 8 + r];
      int s3 = col[base + 12 + r];
      float4 v0 = x4[s0 * 16 + c];
      float4 v1 = x4[s1 * 16 + c];
      float4 v2 = x4[s2 * 16 + c];
      float4 v3 = x4[s3 * 16 + c];
      a0.x += v0.x; a0.y += v0.y; a0.z += v0.z; a0.w += v0.w;
      a1.x += v1.x; a1.y += v1.y; a1.z += v1.z; a1.w += v1.w;
      a2.x += v2.x; a2.y += v2.y; a2.z += v2.z; a2.w += v2.w;
      a3.x += v3.x; a3.y += v3.y; a3.z += v3.z; a3.w += v3.w;
    }
    if (base + 4 <= rp1) {
      int s0 = col[base + r];
      float4 v0 = x4[s0 * 16 + c];
      a0.x += v0.x; a0.y += v0.y; a0.z += v0.z; a0.w += v0.w;
      base += 4;
    }
    if (base + 4 <= rp1) {
      int s1 = col[base + r];
      float4 v1 = x4[s1 * 16 + c];
      a1.x += v1.x; a1.y += v1.y; a1.z += v1.z; a1.w += v1.w;
      base += 4;
    }
    if (base + 4 <= rp1) {
      int s2 = col[base + r];
      float4 v2 = x4[s2 * 16 + c];
      a2.x += v2.x; a2.y += v2.y; a2.z += v2.z; a2.w += v2.w;
      base += 4;
    }
    if (base + r < rp1) {
      int s3 = col[base + r];
      float4 v3 = x4[s3 * 16 + c];
      a3.x += v3.x; a3.y += v3.y; a3.z += v3.z; a3.w += v3.w;
    }
    float4 a;
    a.x = (a0.x + a1.x) + (a2.x + a3.x);
    a.y = (a0.y + a1.y) + (a2.y + a3.y);
    a.z = (a0.z + a1.z) + (a2.z + a3.z);
    a.w = (a0.w + a1.w) + (a2.w + a3.w);
    a.x += __shfl_xor(a.x, 16); a.y += __shfl_xor(a.y, 16);
    a.z += __shfl_xor(a.z, 16); a.w += __shfl_xor(a.w, 16);
    a.x += __shfl_xor(a.x, 32); a.y += __shfl_xor(a.y, 32);
    a.z += __shfl_xor(a.z, 32); a.w += __shfl_xor(a.w, 32);

    if (r == 0) {
      float id = 1.0f / (float)max(rp1 - rp0, 1);
      float4 o;
      o.x = a.x * id; o.y = a.y * id; o.z = a.z * id; o.w = a.w * id;
      ((float4*)&rowS[wv][it][0])[c] = o;
      ((float4*)&rowS[wv][it][0])[16 + c] = root;
    }
  }

  // pin all park-writes before any park-read (R6-proven replay-race fence)
  asm volatile("s_waitcnt lgkmcnt(0)" ::: "memory");
  __builtin_amdgcn_sched_barrier(0);

  // ---- phase 2: batched update, lane = output feature j ----
  const float4* row0 = (const float4*)&rowS[wv][0][0];
  const float4* row1 = (const float4*)&rowS[wv][1][0];
  const float4* row2 = (const float4*)&rowS[wv][2][0];
  const float4* row3 = (const float4*)&rowS[wv][3][0];
  float acc0 = 0.f, acc1 = 0.f, acc2 = 0.f, acc3 = 0.f;
#pragma unroll 2
  for (int k4 = 0; k4 < 16; ++k4) {
    float4 g0 = row0[k4], t0 = row0[16 + k4];
    float4 g1 = row1[k4], t1 = row1[16 + k4];
    float4 g2 = row2[k4], t2 = row2[16 + k4];
    float4 g3 = row3[k4], t3 = row3[16 + k4];
    int k = k4 * 4;
    float wl0 = WlS[(k + 0) * WSTR + lane], wr0 = WrS[(k + 0) * WSTR + lane];
    float wl1 = WlS[(k + 1) * WSTR + lane], wr1 = WrS[(k + 1) * WSTR + lane];
    float wl2 = WlS[(k + 2) * WSTR + lane], wr2 = WrS[(k + 2) * WSTR + lane];
    float wl3 = WlS[(k + 3) * WSTR + lane], wr3 = WrS[(k + 3) * WSTR + lane];
    acc0 += g0.x * wl0 + g0.y * wl1 + g0.z * wl2 + g0.w * wl3
          + t0.x * wr0 + t0.y * wr1 + t0.z * wr2 + t0.w * wr3;
    acc1 += g1.x * wl0 + g1.y * wl1 + g1.z * wl2 + g1.w * wl3
          + t1.x * wr0 + t1.y * wr1 + t1.z * wr2 + t1.w * wr3;
    acc2 += g2.x * wl0 + g2.y * wl1 + g2.z * wl2 + g2.w * wl3
          + t2.x * wr0 + t2.y * wr1 + t2.z * wr2 + t2.w * wr3;
    acc3 += g3.x * wl0 + g3.y * wl1 + g3.z * wl2 + g3.w * wl3
          + t3.x * wr0 + t3.y * wr1 + t3.z * wr2 + t3.w * wr3;
  }
  float bias = bs[lane];
  xn[(nbase + 0) * HID + lane] = fmaxf(acc0 + bias, 0.f);
  xn[(nbase + 1) * HID + lane] = fmaxf(acc1 + bias, 0.f);
  xn[(nbase + 2) * HID + lane] = fmaxf(acc2 + bias, 0.f);
  xn[(nbase + 3) * HID + lane] = fmaxf(acc3 + bias, 0.f);
}

// ---------------------------------------------------------------------------
extern "C" void kernel_launch(void* const* d_in, const int* in_sizes, int n_in,
                              void* d_out, int out_size, void* d_ws, size_t ws_size,
                              hipStream_t stream) {
  const float* track_x  = (const float*)d_in[0];
  const int*   pl_tr_s  = (const int*)d_in[1];
  const int*   pl_tr_d  = (const int*)d_in[2];
  const int*   tr_ar_s  = (const int*)d_in[3];
  const int*   tr_ar_d  = (const int*)d_in[4];
  const float* pl_emb   = (const float*)d_in[5];
  const float* ar_emb   = (const float*)d_in[6];
  const float* track_W  = (const float*)d_in[7];
  const float* track_b  = (const float*)d_in[8];
  const float* type_emb = (const float*)d_in[9];
  const float* conv_Wl  = (const float*)d_in[10];
  const float* conv_bl  = (const float*)d_in[11];
  const float* conv_Wr  = (const float*)d_in[12];

  float* x = (float*)d_out;                      // node state (NN*64)

  // workspace: xalt ALIASES [pkd|tab] -- pkd/tab are dead once k_fill3 has
  // produced rowptr+col; xalt is first written by the layer-0 fused kernel
  // (stream-ordered after fill3). Total: 40.96 (xalt region, covers pkd
  // 16.81 + tab 1.29) + col 16.8 + rowptr 0.64 + btot 4KB = ~58.4 MB.
  char* w = (char*)d_ws;
  float* xalt   = (float*)w;
  int*   pkd    = (int*)w;
  int*   tab    = (int*)(w + (size_t)PKD_CAP * 4);
  w += (size_t)NN * HID * 4;
  int*   col    = (int*)w;    w += (size_t)E_TOT * 4;
  int*   rowptr = (int*)w;    w += (size_t)(NN + 1) * 4;
  int*   btot   = (int*)w;    // NBUCK ints

  k_init_emb<<<(NUM_PL + NUM_AR) * HID / 256, 256, 0, stream>>>(
      pl_emb, ar_emb, type_emb, x);
  k_track_lin<<<NUM_TR / 32, 256, 0, stream>>>(
      track_x, track_W, track_b, type_emb, x);

  // CSR build: bin -> bucket totals -> bucket scan -> count+scan+fill
  k_bin<<<NBLK_BIN, 256, 0, stream>>>(
      pl_tr_s, pl_tr_d, tr_ar_s, tr_ar_d, pkd, tab);
  k_btot<<<(NBUCK + 255) / 256, 256, 0, stream>>>(tab, btot);
  k_bscan<<<1, 1024, 0, stream>>>(btot);
  k_fill3<<<NBUCK, 256, 0, stream>>>(tab, pkd, btot, rowptr, col);

  // fused gather+update, ping-pong x <-> xalt (2 layers -> ends in x=d_out)
  k_gather_update<<<NN / 32, 512, 0, stream>>>(
      rowptr, col, x, conv_Wl, conv_bl, conv_Wr, xalt);
  k_gather_update<<<NN / 32, 512, 0, stream>>>(
      rowptr, col, xalt, conv_Wl + HID * HID, conv_bl + HID,
      conv_Wr + HID * HID, x);
}